// Round 1
// baseline (308.161 us; speedup 1.0000x reference)
//
#include <hip/hip_runtime.h>
#include <hip/hip_bf16.h>

typedef __attribute__((ext_vector_type(4))) float f32x4;
typedef __attribute__((ext_vector_type(8))) short s16x8;
typedef __attribute__((ext_vector_type(8))) __bf16 bf16x8;

#define DEV static __device__ __forceinline__

DEV float bf2f(ushort u){
  unsigned x = ((unsigned)u) << 16;
  return __builtin_bit_cast(float, x);
}
DEV ushort f2bf(float f){
  unsigned x = __builtin_bit_cast(unsigned, f);
  x += 0x7fffu + ((x >> 16) & 1u);
  return (ushort)(x >> 16);
}
DEV void load_lds16(const void* g, void* l){
  __builtin_amdgcn_global_load_lds((const __attribute__((address_space(1))) void*)g,
                                   (__attribute__((address_space(3))) void*)l, 16, 0, 0);
}

// ---------------- stage 0a: x fp32 -> bf16 ----------------
__global__ __launch_bounds__(256) void k_cvt_x(const float* __restrict__ x,
                                               ushort* __restrict__ xb, int n8){
  int i = blockIdx.x * 256 + threadIdx.x;
  if (i >= n8) return;
  const f32x4* p = (const f32x4*)(x + (size_t)i * 8);
  f32x4 a = p[0], b = p[1];
  s16x8 o;
  o[0]=(short)f2bf(a[0]); o[1]=(short)f2bf(a[1]); o[2]=(short)f2bf(a[2]); o[3]=(short)f2bf(a[3]);
  o[4]=(short)f2bf(b[0]); o[5]=(short)f2bf(b[1]); o[6]=(short)f2bf(b[2]); o[7]=(short)f2bf(b[3]);
  *(s16x8*)(xb + (size_t)i * 8) = o;
}

// ---------------- stage 0b: W [K][N] fp32 -> Wt [N][K] bf16 ----------------
__global__ void k_transposeW(const float* __restrict__ Wq, const float* __restrict__ Wk,
                             const float* __restrict__ Wv, const float* __restrict__ Wp,
                             ushort* __restrict__ qkvT, ushort* __restrict__ wpT){
  __shared__ float tile[32][33];
  int z = blockIdx.z;
  const float* W = (z == 0) ? Wq : (z == 1) ? Wk : (z == 2) ? Wv : Wp;
  ushort* out = (z < 3) ? (qkvT + (size_t)z * 1024 * 1024) : wpT;
  int bx = blockIdx.x * 32, by = blockIdx.y * 32;
  int tx = threadIdx.x, ty = threadIdx.y;
  #pragma unroll
  for (int j = 0; j < 32; j += 8)
    tile[ty + j][tx] = W[(size_t)(by + ty + j) * 1024 + bx + tx];
  __syncthreads();
  #pragma unroll
  for (int j = 0; j < 32; j += 8)
    out[(size_t)(bx + ty + j) * 1024 + by + tx] = f2bf(tile[tx][ty + j]);
}

// ---------------- MFMA GEMM: C[M][N] = A[M][K] * Bt[N][K]^T ----------------
// MODE 0: N=3072, epilogue bias + elu+1 on first 2048 cols, bf16 out to q/k/v
// MODE 1: N=1024, epilogue + b0 bias, fp32 out to oF
template<int MODE>
__global__ __launch_bounds__(256, 2) void k_gemm(
    const ushort* __restrict__ A, const ushort* __restrict__ Bt,
    const float* __restrict__ b0, const float* __restrict__ b1, const float* __restrict__ b2,
    ushort* __restrict__ oQ, ushort* __restrict__ oK, ushort* __restrict__ oV,
    float* __restrict__ oF, int N)
{
  const int K = 1024;
  __shared__ ushort ldsA[128 * 64];
  __shared__ ushort ldsB[128 * 64];
  int wg = blockIdx.x;
  int cpx = gridDim.x >> 3;                 // gridDim.x % 8 == 0 for both modes
  wg = (wg & 7) * cpx + (wg >> 3);          // XCD-aware swizzle
  int nbn = N >> 7;
  int bmi = wg / nbn, bni = wg - bmi * nbn;
  int m0 = bmi << 7, n0 = bni << 7;
  int tid = threadIdx.x, wid = tid >> 6, lane = tid & 63;
  int wr = wid >> 1, wc = wid & 1;

  // staging: linear LDS dest, XOR-pre-swizzled global source (rule #21 / T2)
  int srow = lane >> 3;                      // 0..7 (row within 8-row issue)
  int scol = ((lane & 7) ^ srow) << 3;       // swizzled source col (elements)
  const ushort* gA = A  + (size_t)(m0 + srow) * K + scol;
  const ushort* gB = Bt + (size_t)(n0 + srow) * K + scol;

  f32x4 acc[4][4] = {};

  int rbyte = ((wr << 6) + (lane & 15)) << 7;  // A-frag row * 128B
  int cbyte = ((wc << 6) + (lane & 15)) << 7;  // B-frag row * 128B

  for (int k0 = 0; k0 < K; k0 += 64) {
    #pragma unroll
    for (int i = 0; i < 4; ++i) {
      int w4i = (wid << 2) + i;              // 0..15, wave-uniform
      load_lds16(gA + (size_t)(w4i * 8) * K + k0, (char*)ldsA + w4i * 1024);
      load_lds16(gB + (size_t)(w4i * 8) * K + k0, (char*)ldsB + w4i * 1024);
    }
    __syncthreads();
    #pragma unroll
    for (int kk = 0; kk < 2; ++kk) {
      bf16x8 af[4], bfr[4];
      int cofs = (((lane >> 4) << 4) + (kk << 6)) ^ ((lane & 7) << 4);
      #pragma unroll
      for (int m = 0; m < 4; ++m)
        af[m] = *(const bf16x8*)((const char*)ldsA + rbyte + (m << 11) + cofs);
      #pragma unroll
      for (int n = 0; n < 4; ++n)
        bfr[n] = *(const bf16x8*)((const char*)ldsB + cbyte + (n << 11) + cofs);
      #pragma unroll
      for (int m = 0; m < 4; ++m)
        #pragma unroll
        for (int n = 0; n < 4; ++n)
          acc[m][n] = __builtin_amdgcn_mfma_f32_16x16x32_bf16(af[m], bfr[n], acc[m][n], 0, 0, 0);
    }
    __syncthreads();
  }

  int row0 = m0 + (wr << 6) + ((lane >> 4) << 2);
  int col0 = n0 + (wc << 6) + (lane & 15);
  #pragma unroll
  for (int n = 0; n < 4; ++n) {
    int c = col0 + (n << 4);
    if constexpr (MODE == 0) {
      float bias; ushort* dst; bool act;
      if (c < 1024)      { bias = b0[c];        dst = oQ + c;          act = true;  }
      else if (c < 2048) { bias = b1[c - 1024]; dst = oK + (c - 1024); act = true;  }
      else               { bias = b2[c - 2048]; dst = oV + (c - 2048); act = false; }
      #pragma unroll
      for (int m = 0; m < 4; ++m) {
        int r = row0 + (m << 4);
        #pragma unroll
        for (int j = 0; j < 4; ++j) {
          float v = acc[m][n][j] + bias;
          if (act) v = (v > 0.f) ? (v + 1.f) : __expf(v);   // elu(v)+1
          dst[(size_t)(r + j) * 1024] = f2bf(v);
        }
      }
    } else {
      float bias = b0[c];
      #pragma unroll
      for (int m = 0; m < 4; ++m) {
        int r = row0 + (m << 4);
        #pragma unroll
        for (int j = 0; j < 4; ++j)
          oF[(size_t)(r + j) * 1024 + c] = acc[m][n][j] + bias;
      }
    }
  }
}

// ---------------- stage 2: kv[bh][64][64] = k^T v ; sumk[bh][64] ----------------
__global__ __launch_bounds__(256, 2) void k_kv(
    const ushort* __restrict__ kbuf, const ushort* __restrict__ vbuf,
    float* __restrict__ kvg, float* __restrict__ sumkg)
{
  __shared__ ushort lds[8192];               // Ks 8KB | Vs 8KB ; reused as fp32 red
  int bh = blockIdx.x >> 3, chunk = blockIdx.x & 7;
  int b = bh >> 4, h = bh & 15;
  int tid = threadIdx.x, wid = tid >> 6, lane = tid & 63;
  int d0 = (lane >> 3) << 3, e0 = (lane & 7) << 3;
  float acc[8][8] = {};
  float sk[8] = {};
  size_t rowbase = ((size_t)b * 4096 + chunk * 512) * 1024 + h * 64;
  int srow = lane >> 3, scolel = (lane & 7) * 8;

  for (int c = 0; c < 8; ++c) {
    #pragma unroll
    for (int i = 0; i < 2; ++i) {
      int w2i = (wid << 1) + i;              // 0..7, wave-uniform
      size_t g = rowbase + (size_t)(c * 64 + w2i * 8 + srow) * 1024 + scolel;
      load_lds16(kbuf + g, (char*)lds + w2i * 1024);
      load_lds16(vbuf + g, (char*)lds + 8192 + w2i * 1024);
    }
    __syncthreads();
    const ushort* Ks = lds;
    const ushort* Vs = lds + 4096;
    #pragma unroll
    for (int t = 0; t < 16; ++t) {
      int nn = (wid << 4) + t;
      s16x8 k8 = *(const s16x8*)(Ks + nn * 64 + d0);
      s16x8 v8 = *(const s16x8*)(Vs + nn * 64 + e0);
      float kf[8], vf[8];
      #pragma unroll
      for (int i = 0; i < 8; ++i) { kf[i] = bf2f((ushort)k8[i]); vf[i] = bf2f((ushort)v8[i]); }
      #pragma unroll
      for (int i = 0; i < 8; ++i) {
        sk[i] += kf[i];
        #pragma unroll
        for (int j = 0; j < 8; ++j) acc[i][j] += kf[i] * vf[j];
      }
    }
    __syncthreads();
  }
  // cross-wave reduce in LDS (16KB fp32)
  float* red = (float*)lds;
  for (int w = 0; w < 4; ++w) {
    if (wid == w) {
      #pragma unroll
      for (int i = 0; i < 8; ++i)
        #pragma unroll
        for (int j = 0; j < 8; ++j) {
          int idx = (d0 + i) * 64 + e0 + j;
          if (w == 0) red[idx] = acc[i][j];
          else        red[idx] += acc[i][j];
        }
    }
    __syncthreads();
  }
  float* kvo = kvg + bh * 4096;
  #pragma unroll
  for (int i = 0; i < 16; ++i) {
    int idx = tid + i * 256;
    atomicAdd(&kvo[idx], red[idx]);
  }
  if ((lane & 7) == 0) {
    #pragma unroll
    for (int i = 0; i < 8; ++i) atomicAdd(&sumkg[bh * 64 + d0 + i], sk[i]);
  }
}

// ---------------- stage 3: y = (q @ kv) / (q . sumk), bf16 out ----------------
__global__ __launch_bounds__(256, 2) void k_num(
    const ushort* __restrict__ qbuf, const float* __restrict__ kvg,
    const float* __restrict__ sumkg, ushort* __restrict__ ybuf)
{
  __shared__ float kvs[4096];
  __shared__ float sks[64];
  int bh = blockIdx.x >> 5, ch = blockIdx.x & 31;
  int b = bh >> 4, h = bh & 15;
  int tid = threadIdx.x;
  #pragma unroll
  for (int i = 0; i < 16; ++i) kvs[tid + i * 256] = kvg[bh * 4096 + tid + i * 256];
  if (tid < 64) sks[tid] = sumkg[bh * 64 + tid];
  __syncthreads();

  int rl = tid >> 2, eq = (tid & 3) << 4;
  size_t row0 = (size_t)b * 4096 + ch * 128 + rl;     // + row0+64 = second row
  const ushort* q0 = qbuf + row0 * 1024 + h * 64;
  const ushort* q1 = q0 + (size_t)64 * 1024;
  s16x8 qa[8], qb[8];
  #pragma unroll
  for (int i = 0; i < 8; ++i) { qa[i] = *(const s16x8*)(q0 + i * 8); qb[i] = *(const s16x8*)(q1 + i * 8); }

  float a0[16] = {}, a1[16] = {};
  float den0 = 0.f, den1 = 0.f;
  #pragma unroll
  for (int d = 0; d < 64; ++d) {
    float x0 = bf2f((ushort)qa[d >> 3][d & 7]);
    float x1 = bf2f((ushort)qb[d >> 3][d & 7]);
    float s = sks[d];
    den0 += x0 * s; den1 += x1 * s;
    const f32x4* kr = (const f32x4*)&kvs[d * 64 + eq];
    #pragma unroll
    for (int j = 0; j < 4; ++j) {
      f32x4 k4 = kr[j];
      #pragma unroll
      for (int u = 0; u < 4; ++u) {
        a0[j * 4 + u] += x0 * k4[u];
        a1[j * 4 + u] += x1 * k4[u];
      }
    }
  }
  float i0 = 1.f / den0, i1 = 1.f / den1;
  ushort* y0 = ybuf + row0 * 1024 + h * 64 + eq;
  ushort* y1 = y0 + (size_t)64 * 1024;
  s16x8 p0[2], p1[2];
  #pragma unroll
  for (int j = 0; j < 16; ++j) {
    p0[j >> 3][j & 7] = (short)f2bf(a0[j] * i0);
    p1[j >> 3][j & 7] = (short)f2bf(a1[j] * i1);
  }
  *(s16x8*)y0 = p0[0]; *((s16x8*)y0 + 1) = p0[1];
  *(s16x8*)y1 = p1[0]; *((s16x8*)y1 + 1) = p1[1];
}

extern "C" void kernel_launch(void* const* d_in, const int* in_sizes, int n_in,
                              void* d_out, int out_size, void* d_ws, size_t ws_size,
                              hipStream_t stream)
{
  const float* x  = (const float*)d_in[0];
  const float* Wq = (const float*)d_in[1];
  const float* bq = (const float*)d_in[2];
  const float* Wk = (const float*)d_in[3];
  const float* bk = (const float*)d_in[4];
  const float* Wv = (const float*)d_in[5];
  const float* bv = (const float*)d_in[6];
  const float* Wp = (const float*)d_in[7];
  const float* bp = (const float*)d_in[8];

  char* ws = (char*)d_ws;
  ushort* xb    = (ushort*)(ws + 0);          // 33,554,432 B  x in bf16
  ushort* qkvT  = (ushort*)(ws + 33554432);   //  6,291,456 B  [Wq|Wk|Wv]^T bf16
  ushort* wpT   = (ushort*)(ws + 39845888);   //  2,097,152 B  Wp^T bf16
  ushort* ybuf  = (ushort*)(ws + 41943040);   // 33,554,432 B  k (then aliased as y)
  float*  kvg   = (float*)(ws + 75497472);    //  1,048,576 B  kv fp32
  float*  sumkg = (float*)(ws + 76546048);    //     16,384 B  sum_k fp32
  // total ws use: 76,562,432 B

  // v and q live in d_out (67,108,864 B of scratch, dead before final GEMM)
  ushort* vbuf = (ushort*)d_out;
  ushort* qbuf = (ushort*)d_out + 16777216;
  ushort* kbuf = ybuf;

  hipMemsetAsync(kvg, 0, 1064960, stream);                       // kv + sumk
  k_cvt_x<<<8192, 256, 0, stream>>>(x, xb, 2097152);
  k_transposeW<<<dim3(32, 32, 4), dim3(32, 8), 0, stream>>>(Wq, Wk, Wv, Wp, qkvT, wpT);
  k_gemm<0><<<3072, 256, 0, stream>>>(xb, qkvT, bq, bk, bv, qbuf, kbuf, vbuf, nullptr, 3072);
  k_kv<<<512, 256, 0, stream>>>(kbuf, vbuf, kvg, sumkg);
  k_num<<<2048, 256, 0, stream>>>(qbuf, kvg, sumkg, ybuf);
  k_gemm<1><<<1024, 256, 0, stream>>>(ybuf, wpT, bp, nullptr, nullptr,
                                      nullptr, nullptr, nullptr, (float*)d_out, 1024);
}